// Round 8
// baseline (347.751 us; speedup 1.0000x reference)
//
#include <hip/hip_runtime.h>
#include <cstdint>
#include <cstddef>

// Problem constants (fixed by the reference)
#define B_  2
#define T_  1024
#define C_  2048
#define H_  32
#define BT_ (B_*T_)
static constexpr float EPS_GN = 1e-5f * 64.0f;

using short8 = __attribute__((ext_vector_type(8))) short;
using f32x4  = __attribute__((ext_vector_type(4))) float;
typedef unsigned short bfu16;

__device__ __forceinline__ bfu16 f2b(float f) {
  uint32_t x = __float_as_uint(f);
  uint32_t r = (x + 0x7FFFu + ((x >> 16) & 1u)) >> 16;
  return (bfu16)r;
}
__device__ __forceinline__ float b2f(bfu16 h) {
  return __uint_as_float(((uint32_t)h) << 16);
}

__device__ __forceinline__ void gload16(const bfu16* g, bfu16* l) {
  __builtin_amdgcn_global_load_lds((__attribute__((address_space(1))) void*)g,
                                   (__attribute__((address_space(3))) void*)l,
                                   16, 0, 0);
}

// ---------------------------------------------------------------------------
// gemm256: 256x256 tile, BK=64, 512 threads (8 waves 2Mx4N), dbuf LDS 128KB.
// Schedule: {STAGE_A(kt+1); STAGE_B(kt+1); vmcnt(8); barrier; per-ks
// {ds_read frags; MFMA}; barrier} -- both next-tile stages get a full
// iteration of flight; vmcnt(8) = exactly the 8 loads of tile kt+1 remain.
// LDS XOR-swizzle: source col ^((row&7)<<3), read col ^((lane&7)<<3).
// XCD-aware bijective block swizzle (nwg % 8 == 0 required).
// kSplit==1: batched over z (A=aArr[z], Bt+=z*bStr, out+=z*oStr).
// kSplit>1 : z = K-chunk of A/Bt (out+=z*oStr, f32 partials).
// ---------------------------------------------------------------------------
struct G256P {
  const bfu16* Bt; float* of;
  size_t bStr, oStr;
  int ldk, nkt, kSplit;
  const bfu16* aArr[4];
};

__global__ __launch_bounds__(512, 2)
void gemm256(G256P p)
{
  extern __shared__ __align__(16) bfu16 sm[];   // A0,A1,B0,B1 each 256*64
  const int tid  = threadIdx.x;
  const int nwg = gridDim.x * gridDim.y * gridDim.z;
  int lin = blockIdx.x + gridDim.x * (blockIdx.y + gridDim.y * blockIdx.z);
  lin = (lin & 7) * (nwg >> 3) + (lin >> 3);
  const int bx = lin % gridDim.x;
  const int by = (lin / gridDim.x) % gridDim.y;
  const int z  = lin / (gridDim.x * gridDim.y);
  const int m0   = by * 256, n0 = bx * 256;
  const int lane = tid & 63;
  const int wv   = tid >> 6;
  const int wm   = wv >> 2, wn = wv & 3;
  const int ldk  = p.ldk;

  const bfu16* A;
  size_t koff;
  if (p.kSplit > 1) { A = p.aArr[0]; koff = (size_t)z * p.nkt * 64; }
  else              { A = p.aArr[z]; koff = 0; }
  const bfu16* Bt = p.Bt + (size_t)z * p.bStr;

  const int srow = tid >> 3;        // 0..63
  const int scol = (tid & 7) * 8;   // 0..56
  const int sswz = (srow & 7) << 3; // source-side inverse swizzle
  const bfu16* gA = A  + (size_t)(m0 + srow) * ldk + koff + (scol ^ sswz);
  const bfu16* gB = Bt + (size_t)(n0 + srow) * ldk + koff + (scol ^ sswz);

  auto STAGE_A = [&](bfu16* dst, int kt) {
    const bfu16* g = gA + (size_t)kt * 64;
    bfu16* l = dst + srow * 64 + scol;
#pragma unroll
    for (int it = 0; it < 4; ++it)
      gload16(g + (size_t)it * 64 * ldk, l + it * 4096);
  };
  auto STAGE_B = [&](bfu16* dst, int kt) {
    const bfu16* g = gB + (size_t)kt * 64;
    bfu16* l = dst + srow * 64 + scol;
#pragma unroll
    for (int it = 0; it < 4; ++it)
      gload16(g + (size_t)it * 64 * ldk, l + it * 4096);
  };

  f32x4 acc[8][4];
  const f32x4 zero = {0.f, 0.f, 0.f, 0.f};
#pragma unroll
  for (int i = 0; i < 8; ++i)
#pragma unroll
    for (int j = 0; j < 4; ++j) acc[i][j] = zero;

  STAGE_A(sm, 0);
  STAGE_B(sm + 32768, 0);           // 8 outstanding

  const int rswz = (lane & 7) << 3; // read-side swizzle

  for (int kt = 0; kt < p.nkt; ++kt) {
    bfu16* curA = sm + (kt & 1) * 16384;
    bfu16* curB = sm + 32768 + (kt & 1) * 16384;
    bfu16* nxtA = sm + ((kt & 1) ^ 1) * 16384;
    bfu16* nxtB = sm + 32768 + ((kt & 1) ^ 1) * 16384;
    const bool more = (kt + 1 < p.nkt);
    if (more) {
      STAGE_A(nxtA, kt + 1);
      STAGE_B(nxtB, kt + 1);                       // 16 outstanding
      asm volatile("s_waitcnt vmcnt(8)" ::: "memory");  // tile kt landed
    } else {
      asm volatile("s_waitcnt vmcnt(0)" ::: "memory");
    }
    __builtin_amdgcn_s_barrier();

#pragma unroll
    for (int ks = 0; ks < 2; ++ks) {
      const int ko = (ks * 32 + (lane >> 4) * 8) ^ rswz;
      short8 a[8], b[4];
#pragma unroll
      for (int i = 0; i < 8; ++i)
        a[i] = *(const short8*)(curA + (wm * 128 + i * 16 + (lane & 15)) * 64 + ko);
#pragma unroll
      for (int j = 0; j < 4; ++j)
        b[j] = *(const short8*)(curB + (wn * 64 + j * 16 + (lane & 15)) * 64 + ko);
      __builtin_amdgcn_s_setprio(1);
#pragma unroll
      for (int i = 0; i < 8; ++i)
#pragma unroll
        for (int j = 0; j < 4; ++j)
          acc[i][j] = __builtin_amdgcn_mfma_f32_16x16x32_bf16(a[i], b[j], acc[i][j], 0, 0, 0);
      __builtin_amdgcn_s_setprio(0);
    }
    __builtin_amdgcn_s_barrier();
  }

  float* o = p.of + (size_t)z * p.oStr;
  const int cb = n0 + wn * 64 + (lane & 15);
  const int rb = m0 + wm * 128 + ((lane >> 4) << 2);
#pragma unroll
  for (int i = 0; i < 8; ++i)
#pragma unroll
    for (int j = 0; j < 4; ++j) {
      int col = cb + j * 16;
#pragma unroll
      for (int q = 0; q < 4; ++q)
        o[(size_t)(rb + i * 16 + q) * 2048 + col] = acc[i][j][q];
    }
}

// ---------------------------------------------------------------------------
// 128x128 GEMM for the small/odd shapes.
// MODE 4: of = -exp(vArr[0][col] + acc)   (fused lw = -exp(w))
// MODE 5: split-K partials
// MODE 7: batched-5 token-mix epilogue (x and xx both bf16)
// ---------------------------------------------------------------------------
struct GemmP {
  const bfu16* A; const bfu16* Bt;
  float* of; bfu16* ob;
  const bfu16* xh; const bfu16* xxh;
  int ldk, kIters, kChunk, ldo;
  size_t pStride, aStr, bStr, oStr;
  const float* vArr[5];
};

template<int MODE>
__global__ __launch_bounds__(256)
void gemm_k(GemmP p)
{
  __shared__ alignas(16) bfu16 As[128*64];
  __shared__ alignas(16) bfu16 Bs[128*64];
  const int tid  = threadIdx.x;
  const int z    = blockIdx.z;
  const int m0   = blockIdx.y * 128, n0 = blockIdx.x * 128;
  const int lane = tid & 63;
  const int wv   = tid >> 6;
  const int wr   = (wv >> 1) * 64, wc = (wv & 1) * 64;

  const bfu16* A  = p.A;
  const bfu16* Bt = p.Bt;
  size_t koff = 0;
  if constexpr (MODE == 7) { A += (size_t)z * p.aStr; Bt += (size_t)z * p.bStr; }
  if constexpr (MODE == 5) { koff = (size_t)z * p.kChunk; }

  f32x4 acc[4][4];
  const f32x4 zero = {0.f, 0.f, 0.f, 0.f};
#pragma unroll
  for (int i = 0; i < 4; ++i)
#pragma unroll
    for (int j = 0; j < 4; ++j) acc[i][j] = zero;

  const int srow = tid >> 3;
  const int scol = (tid & 7) * 8;
  const int ldk  = p.ldk;

  for (int kb = 0; kb < p.kIters; ++kb) {
    const bfu16* ga = A  + (size_t)m0 * ldk + koff + kb * 64;
    const bfu16* gb = Bt + (size_t)n0 * ldk + koff + kb * 64;
#pragma unroll
    for (int it = 0; it < 4; ++it) {
      int r = it * 32 + srow;
      gload16(ga + (size_t)r * ldk + scol, As + r * 64 + scol);
      gload16(gb + (size_t)r * ldk + scol, Bs + r * 64 + scol);
    }
    __syncthreads();
#pragma unroll
    for (int kk = 0; kk < 2; ++kk) {
      const int ko = kk * 32 + (lane >> 4) * 8;
      short8 a[4], b[4];
#pragma unroll
      for (int i = 0; i < 4; ++i)
        a[i] = *(const short8*)(As + (wr + i * 16 + (lane & 15)) * 64 + ko);
#pragma unroll
      for (int j = 0; j < 4; ++j)
        b[j] = *(const short8*)(Bs + (wc + j * 16 + (lane & 15)) * 64 + ko);
#pragma unroll
      for (int i = 0; i < 4; ++i)
#pragma unroll
        for (int j = 0; j < 4; ++j)
          acc[i][j] = __builtin_amdgcn_mfma_f32_16x16x32_bf16(a[i], b[j], acc[i][j], 0, 0, 0);
    }
    __syncthreads();
  }

  const int cb = n0 + wc + (lane & 15);
  const int rb = m0 + wr + ((lane >> 4) << 2);
#pragma unroll
  for (int i = 0; i < 4; ++i) {
#pragma unroll
    for (int j = 0; j < 4; ++j) {
      int col = cb + j * 16;
#pragma unroll
      for (int q = 0; q < 4; ++q) {
        int row = rb + i * 16 + q;
        float v = acc[i][j][q];
        if constexpr (MODE == 4) {
          p.of[(size_t)row * p.ldo + col] = -__expf(p.vArr[0][col] + v);
        } else if constexpr (MODE == 5) {
          p.of[(size_t)z * p.pStride + (size_t)row * p.ldo + col] = v;
        } else if constexpr (MODE == 7) {
          size_t idx = (size_t)row * C_ + col;
          (p.ob + (size_t)z * p.oStr)[idx] =
              f2b(b2f(p.xh[idx]) + b2f(p.xxh[idx]) * (p.vArr[z][col] + v));
        }
      }
    }
  }
}

// ---------------------------------------------------------------------------
// split-K reduce + tanh -> bf16.  OUT=0: mtan scatter [f][row][d]; OUT=1: wtan.
// ---------------------------------------------------------------------------
template<int OUT>
__global__ __launch_bounds__(256)
void redk_tanh(const float* __restrict__ part, size_t pStr, int ldo, int ncols,
               bfu16* __restrict__ out)
{
  int id = blockIdx.x * 256 + threadIdx.x;
  int row = id / ncols, col = id % ncols;
  if (row >= BT_) return;
  float v = 0.f;
#pragma unroll
  for (int s = 0; s < 8; ++s) v += part[(size_t)s * pStr + (size_t)row * ldo + col];
  bfu16 tv = f2b(tanhf(v));
  if constexpr (OUT == 0)
    out[((size_t)(col >> 5) * BT_ + row) * 64 + (col & 31)] = tv;
  else
    out[(size_t)row * 64 + col] = tv;
}

__global__ __launch_bounds__(256)
void redk_sum4(const float* __restrict__ p0, float* __restrict__ out)
{
  size_t i = ((size_t)blockIdx.x * 256 + threadIdx.x) * 4;
  const size_t str = (size_t)2048 * 2048;
  float4 a = *(const float4*)(p0 + i);
  float4 b = *(const float4*)(p0 + str + i);
  float4 c = *(const float4*)(p0 + 2 * str + i);
  float4 d = *(const float4*)(p0 + 3 * str + i);
  a.x += b.x + c.x + d.x; a.y += b.y + c.y + d.y;
  a.z += b.z + c.z + d.z; a.w += b.w + c.w + d.w;
  *(float4*)(out + i) = a;
}

// ---------------------------------------------------------------------------
// f32 [R][Cc] -> bf16 dst[c*ldd + r], batched over z. Rows [R,Rpad) zeroed.
// ---------------------------------------------------------------------------
struct TrP { const float* src[5]; bfu16* dst; size_t dStr; int R, Cc, Rpad, ldd; };

__global__ __launch_bounds__(256)
void transpose_k(TrP p)
{
  __shared__ float tile[32][33];
  const float* src = p.src[blockIdx.z];
  bfu16* dst = p.dst + (size_t)blockIdx.z * p.dStr;
  const int tx = threadIdx.x & 31, ty = threadIdx.x >> 5;
  const int r0 = blockIdx.y * 32, c0 = blockIdx.x * 32;
#pragma unroll
  for (int i = 0; i < 4; ++i) {
    int r = r0 + ty + i * 8, c = c0 + tx;
    tile[ty + i * 8][tx] = (r < p.R && c < p.Cc) ? src[(size_t)r * p.Cc + c] : 0.f;
  }
  __syncthreads();
#pragma unroll
  for (int i = 0; i < 4; ++i) {
    int c = c0 + ty + i * 8, r = r0 + tx;
    if (c < p.Cc && r < p.Rpad) dst[(size_t)c * p.ldd + r] = f2b(tile[tx][ty + i * 8]);
  }
}

// ---------------------------------------------------------------------------
// xx = shift(x) - x (bf16) ; xxx = bf16(x + xx*maa_x) ; xh = bf16(x)
// ---------------------------------------------------------------------------
__global__ __launch_bounds__(256)
void prep_xx(const float* __restrict__ x, const float* __restrict__ maa_x,
             bfu16* __restrict__ xxh, bfu16* __restrict__ xxx,
             bfu16* __restrict__ xh)
{
  size_t i = ((size_t)blockIdx.x * 256 + threadIdx.x) * 4;
  int c  = (int)(i & (C_ - 1));
  int bt = (int)(i >> 11);
  int t  = bt & (T_ - 1);
  float4 xv = *(const float4*)(x + i);
  float4 xp = {0.f, 0.f, 0.f, 0.f};
  if (t > 0) xp = *(const float4*)(x + i - C_);
  float4 mx = *(const float4*)(maa_x + c);
  float dx = xp.x - xv.x, dy = xp.y - xv.y, dz = xp.z - xv.z, dw = xp.w - xv.w;
  uint2 w0;
  w0.x = (uint32_t)f2b(dx) | ((uint32_t)f2b(dy) << 16);
  w0.y = (uint32_t)f2b(dz) | ((uint32_t)f2b(dw) << 16);
  *(uint2*)(xxh + i) = w0;
  uint2 w1;
  w1.x = (uint32_t)f2b(xv.x + dx * mx.x) | ((uint32_t)f2b(xv.y + dy * mx.y) << 16);
  w1.y = (uint32_t)f2b(xv.z + dz * mx.z) | ((uint32_t)f2b(xv.w + dw * mx.w) << 16);
  *(uint2*)(xxx + i) = w1;
  uint2 w2;
  w2.x = (uint32_t)f2b(xv.x) | ((uint32_t)f2b(xv.y) << 16);
  w2.y = (uint32_t)f2b(xv.z) | ((uint32_t)f2b(xv.w) << 16);
  *(uint2*)(xh + i) = w2;
}

// ---------------------------------------------------------------------------
// WKV6 chunked scan, chunk L=32. 2048 blocks = B*H*32 chunks, 256 threads.
// ~36 KB LDS -> 4 blocks/CU (vs 79 KB/2 at L=64): scores/O LDS instrs halve
// (L^2 scaling), TLP doubles. w input is ALREADY lw = -exp(w).
// ---------------------------------------------------------------------------
#define S32 68   // LDS row stride (floats) for 32-row tiles

__global__ __launch_bounds__(256)
void wkv_a32(const float* __restrict__ r, const float* __restrict__ k,
             const float* __restrict__ v, const float* __restrict__ w,
             const float* __restrict__ u, float* __restrict__ rp,
             float* __restrict__ y, float* __restrict__ U, float* __restrict__ G)
{
  __shared__ float rw[32 * S32];
  __shared__ float kk[32 * S32];
  __shared__ float vv[32 * S32];
  __shared__ float Ps[32 * S32];
  __shared__ float red[256];
  __shared__ float diag[32];
  __shared__ float Gl[64];

  const int blk = blockIdx.x;
  const int bh = blk >> 5, c = blk & 31;
  const int b = bh >> 5, h = bh & 31;
  const int tid = threadIdx.x;
  const size_t gbase = ((size_t)(b * T_ + c * 32)) * C_ + h * 64;

  // ---- load r,k,v,lw (each thread: 1 row-slice of 8 floats per array)
  {
    const int t = tid >> 3, q = tid & 7;
    const size_t g = gbase + (size_t)t * C_ + q * 8;
    const int l = t * S32 + q * 8;
    *(float4*)(rw + l)     = *(const float4*)(r + g);
    *(float4*)(rw + l + 4) = *(const float4*)(r + g + 4);
    *(float4*)(kk + l)     = *(const float4*)(k + g);
    *(float4*)(kk + l + 4) = *(const float4*)(k + g + 4);
    *(float4*)(vv + l)     = *(const float4*)(v + g);
    *(float4*)(vv + l + 4) = *(const float4*)(v + g + 4);
    *(float4*)(Ps + l)     = *(const float4*)(w + g);
    *(float4*)(Ps + l + 4) = *(const float4*)(w + g + 4);
  }
  __syncthreads();

  // ---- segmented prefix over t (4 segments of 8), per-j
  {
    const int seg = tid >> 6, j = tid & 63;
    float loc = 0.f;
#pragma unroll
    for (int tt = 0; tt < 8; ++tt) loc += Ps[(seg * 8 + tt) * S32 + j];
    red[seg * 64 + j] = loc;
  }
  __syncthreads();
  {
    const int seg = tid >> 6, j = tid & 63;
    float cs = 0.f;
    for (int s = 0; s < seg; ++s) cs += red[s * 64 + j];
    const float uj = u[h * 64 + j];
#pragma unroll
    for (int tt = 0; tt < 8; ++tt) {
      const int a = (seg * 8 + tt) * S32 + j;
      float lw = Ps[a];
      float rv = rw[a] * __expf(cs);
      rw[a] = rv;
      cs += lw;
      float kv = kk[a] * __expf(-cs);
      kk[a] = kv;
      Ps[a] = rv * kv * uj * __expf(lw);   // D (exact)
    }
    if (seg == 3) {
      float Gj = __expf(cs);
      Gl[j] = Gj;
      G[((size_t)bh * 32 + c) * 64 + j] = Gj;
    }
  }
  __syncthreads();

  // ---- diag[t] = sum_j D[t][j]
  {
    const int t = tid & 31, q = tid >> 5;   // q 0..7
    float s = 0.f;
#pragma unroll
    for (int jj = 0; jj < 8; ++jj) s += Ps[t * S32 + q * 8 + jj];
    red[q * 32 + t] = s;
  }
  __syncthreads();
  if (tid < 32) {
    float d = 0.f;
#pragma unroll
    for (int q = 0; q < 8; ++q) d += red[q * 32 + tid];
    diag[tid] = d;
  }
  __syncthreads();

  // ---- scores: 2x2 tiles over 16x16 thread grid, lower-tri
  {
    const int tq = tid >> 4, sq = tid & 15;
    float a00 = 0.f, a01 = 0.f, a10 = 0.f, a11 = 0.f;
    if (sq <= tq) {
      for (int j = 0; j < 64; j += 4) {
        float4 r0 = *(const float4*)(rw + (2 * tq + 0) * S32 + j);
        float4 r1 = *(const float4*)(rw + (2 * tq + 1) * S32 + j);
        float4 k0 = *(const float4*)(kk + (2 * sq + 0) * S32 + j);
        float4 k1 = *(const float4*)(kk + (2 * sq + 1) * S32 + j);
        a00 += r0.x * k0.x + r0.y * k0.y + r0.z * k0.z + r0.w * k0.w;
        a01 += r0.x * k1.x + r0.y * k1.y + r0.z * k1.z + r0.w * k1.w;
        a10 += r1.x * k0.x + r1.y * k0.y + r1.z * k0.z + r1.w * k0.w;
        a11 += r1.x * k1.x + r1.y * k1.y + r1.z * k1.z + r1.w * k1.w;
      }
    }
    __syncthreads();   // everyone done reading D from Ps (diag phase had barrier, but keep write-after-read safe)
    if (sq <= tq) {
      const float av[2][2] = {{a00, a01}, {a10, a11}};
#pragma unroll
      for (int tt = 0; tt < 2; ++tt)
#pragma unroll
        for (int ss = 0; ss < 2; ++ss) {
          int t = 2 * tq + tt, s = 2 * sq + ss;
          Ps[t * S32 + s] = (s < t) ? av[tt][ss] : (s == t ? diag[t] : 0.f);
        }
    }
  }
  __syncthreads();

  // ---- O_intra[t][i] = sum_{s<=t} P[t][s] * v[s][i]  -> y
  {
    const int tq = tid >> 4, iq = tid & 15;
    float o0[4] = {0.f, 0.f, 0.f, 0.f}, o1[4] = {0.f, 0.f, 0.f, 0.f};
    const int tmax = 2 * tq + 1;
    for (int s = 0; s <= tmax; ++s) {
      float4 vx = *(const float4*)(vv + s * S32 + iq * 4);
      float p0 = Ps[(2 * tq + 0) * S32 + s];   // 0 for s > 2tq (diag block)
      float p1 = Ps[(2 * tq + 1) * S32 + s];
      o0[0] += p0 * vx.x; o0[1] += p0 * vx.y; o0[2] += p0 * vx.z; o0[3] += p0 * vx.w;
      o1[0] += p1 * vx.x; o1[1] += p1 * vx.y; o1[2] += p1 * vx.z; o1[3] += p1 * vx.w;
    }
    float4 w0 = {o0[0], o0[1], o0[2], o0[3]};
    float4 w1 = {o1[0], o1[1], o1[2], o1[3]};
    *(float4*)(y + gbase + (size_t)(2 * tq + 0) * C_ + iq * 4) = w0;
    *(float4*)(y + gbase + (size_t)(2 * tq + 1) * C_ + iq * 4) = w1;
  }

  // ---- U[j][i] = G[j] * sum_s k~[s][j] * v[s][i]
  {
    const int jq = tid >> 4, iq = tid & 15;
    float ua[4][4] = {{0.f}};
    for (int s = 0; s < 32; ++s) {
      float4 kx = *(const float4*)(kk + s * S32 + jq * 4);
      float4 vx = *(const float4*)(vv + s * S32 + iq * 4);
      ua[0][0] += kx.x * vx.x; ua[0][1] += kx.x * vx.y; ua[0][2] += kx.x * vx.z; ua[0][3] += kx.x * vx.w;
      ua[1][0] += kx.y * vx.x; ua[1][1] += kx.y * vx.y; ua[1][2] += kx.y * vx.z; ua[1][3] += kx.y * vx.w;
      ua[2][0] += kx.z * vx.x; ua[2][1] += kx.z * vx.y; ua[2][2] += kx.z * vx.z; ua[2][3] += kx.z * vx.w;
      ua[3][0] += kx.w * vx.x; ua[3][1] += kx.w * vx.y; ua[3][2] += kx.w * vx.z; ua[3][3] += kx.w * vx.w;
    }
    const size_t ub = ((size_t)bh * 32 + c) * 4096;
#pragma unroll
    for (int jj = 0; jj < 4; ++jj) {
      float g = Gl[jq * 4 + jj];
      float4 uv = {ua[jj][0] * g, ua[jj][1] * g, ua[jj][2] * g, ua[jj][3] * g};
      *(float4*)(U + ub + (size_t)(jq * 4 + jj) * 64 + iq * 4) = uv;
    }
  }

  // ---- write r' back (for phase C)
  {
    const int t = tid >> 3, q = tid & 7;
    const size_t g = gbase + (size_t)t * C_ + q * 8;
    const int l = t * S32 + q * 8;
    *(float4*)(rp + g)     = *(const float4*)(rw + l);
    *(float4*)(rp + g + 4) = *(const float4*)(rw + l + 4);
  }
}

__global__ __launch_bounds__(256)
void wkv_b32(const float* __restrict__ U, const float* __restrict__ G,
             float* __restrict__ Sbuf)
{
  const int bh = blockIdx.x;
  const int tid = threadIdx.x;
  const int i = tid & 63, jq = tid >> 6;
  __shared__ float Gl[64];
  float S[16];
#pragma unroll
  for (int jj = 0; jj < 16; ++jj) S[jj] = 0.f;
  for (int c = 0; c < 32; ++c) {
    if (tid < 64) Gl[tid] = G[((size_t)bh * 32 + c) * 64 + tid];
    __syncthreads();
    const size_t base = ((size_t)bh * 32 + c) * 4096;
#pragma unroll
    for (int jj = 0; jj < 16; ++jj) {
      const int j = jq * 16 + jj;
      Sbuf[base + (size_t)j * 64 + i] = S[jj];
      S[jj] = Gl[j] * S[jj] + U[base + (size_t)j * 64 + i];
    }
    __syncthreads();
  }
}

__global__ __launch_bounds__(256)
void wkv_c32(const float* __restrict__ rp, const float* __restrict__ Sbuf,
             float* __restrict__ y)
{
  __shared__ float Sl[64 * S32];
  __shared__ float rl[32 * S32];
  const int blk = blockIdx.x;
  const int bh = blk >> 5, c = blk & 31;
  const int b = bh >> 5, h = bh & 31;
  const int tid = threadIdx.x;
  const size_t gbase = ((size_t)(b * T_ + c * 32)) * C_ + h * 64;
  {
    const int j = tid >> 2, q = tid & 3;     // S: 64 rows x 64 cols
    const size_t sb = ((size_t)bh * 32 + c) * 4096 + (size_t)j * 64 + q * 16;
    const int l = j * S32 + q * 16;
#pragma unroll
    for (int p = 0; p < 4; ++p)
      *(float4*)(Sl + l + p * 4) = *(const float4*)(Sbuf + sb + p * 4);
    const int t = tid >> 3, q8 = tid & 7;    // r': 32 rows x 64 cols
    const size_t gr = gbase + (size_t)t * C_ + q8 * 8;
    const int lr = t * S32 + q8 * 8;
    *(float4*)(rl + lr)     = *(const float4*)(rp + gr);
    *(float4*)(rl + lr + 4) = *(const float4*)(rp + gr + 4);
  }
  __syncthreads();
  const int tq = tid >> 4, iq = tid & 15;
  float o0[4] = {0.f, 0.f, 0.f, 0.f}, o1[4] = {0.f, 0.f, 0.f, 0.f};
  for (int j = 0; j < 64; ++j) {
    float4 sv = *(const float4*)(Sl + j * S32 + iq * 4);
    float r0 = rl[(2 * tq + 0) * S32 + j];
    float r1 = rl[(2 * tq + 1) * S32 + j];
    o0[0] += r0 * sv.x; o0[1] += r0 * sv.y; o0[2] += r0 * sv.z; o0[3] += r0 * sv.w;
    o1[0] += r1 * sv.x; o1[1] += r1 * sv.y; o1[2] += r1 * sv.z; o1[3] += r1 * sv.w;
  }
  {
    float* yp = y + gbase + (size_t)(2 * tq + 0) * C_ + iq * 4;
    float4 yv = *(const float4*)yp;
    yv.x += o0[0]; yv.y += o0[1]; yv.z += o0[2]; yv.w += o0[3];
    *(float4*)yp = yv;
    yp = y + gbase + (size_t)(2 * tq + 1) * C_ + iq * 4;
    yv = *(const float4*)yp;
    yv.x += o1[0]; yv.y += o1[1]; yv.z += o1[2]; yv.w += o1[3];
    *(float4*)yp = yv;
  }
}

// ---------------------------------------------------------------------------
// GroupNorm(32 groups of 64) * silu(gpre) -> bf16
// ---------------------------------------------------------------------------
__global__ __launch_bounds__(256)
void gnorm_kernel(const float* __restrict__ y, const float* __restrict__ gpre,
                  const float* __restrict__ lng, const float* __restrict__ lnb,
                  bfu16* __restrict__ yg)
{
  const int bt = blockIdx.x;
  const int wv = threadIdx.x >> 6, lane = threadIdx.x & 63;
#pragma unroll
  for (int it = 0; it < 8; ++it) {
    int hh = it * 4 + wv;
    int c = hh * 64 + lane;
    size_t idx = (size_t)bt * C_ + c;
    float yv = y[idx];
    float s = yv, sq = yv * yv;
#pragma unroll
    for (int m = 1; m < 64; m <<= 1) {
      s  += __shfl_xor(s, m, 64);
      sq += __shfl_xor(sq, m, 64);
    }
    float mu  = s * (1.f / 64.f);
    float var = sq * (1.f / 64.f) - mu * mu;
    float yn  = (yv - mu) * rsqrtf(var + EPS_GN);
    yn = yn * lng[c] + lnb[c];
    float gp = gpre[idx];
    float gs = gp / (1.f + __expf(-gp));
    yg[idx] = f2b(yn * gs);
  }
}

// ---------------------------------------------------------------------------
extern "C" void kernel_launch(void* const* d_in, const int* in_sizes, int n_in,
                              void* d_out, int out_size, void* d_ws, size_t ws_size,
                              hipStream_t stream)
{
  const float* x      = (const float*)d_in[0];
  const float* maa_x  = (const float*)d_in[1];
  const float* maa_w  = (const float*)d_in[2];
  const float* maa_k  = (const float*)d_in[3];
  const float* maa_v  = (const float*)d_in[4];
  const float* maa_r  = (const float*)d_in[5];
  const float* maa_g  = (const float*)d_in[6];
  const float* tdec   = (const float*)d_in[7];
  const float* u      = (const float*)d_in[8];
  const float* maa_w1 = (const float*)d_in[9];
  const float* maa_w2 = (const float*)d_in[10];
  const float* td_w1  = (const float*)d_in[11];
  const float* td_w2  = (const float*)d_in[12];
  const float* lng = (const float*)d_in[18];
  const float* lnb = (const float*)d_in[19];
  float* out = (float*)d_out;

  char* wsp = (char*)d_ws;
  auto alloc = [&](size_t bytes) -> char* {
    char* p = wsp;
    wsp += (bytes + 255) & ~(size_t)255;
    return p;
  };

  bfu16* WT0 = (bfu16*)alloc((size_t)5 * 2048 * 2048 * 2);  // WT[z] = WT0 + z*4M
  bfu16* w1T  = (bfu16*)alloc((size_t)256 * 2048 * 2);
  bfu16* tw1T = (bfu16*)alloc((size_t)128 * 2048 * 2);
  bfu16* tw2T = (bfu16*)alloc((size_t)2048 * 64 * 2);
  bfu16* w2T  = (bfu16*)alloc((size_t)5 * 2048 * 64 * 2);
  float* ybuf = (float*)alloc((size_t)BT_ * C_ * 4);
  bfu16* xxh  = (bfu16*)alloc((size_t)BT_ * C_ * 2);
  bfu16* xxx  = (bfu16*)alloc((size_t)BT_ * C_ * 2);
  bfu16* xh   = (bfu16*)alloc((size_t)BT_ * C_ * 2);
  bfu16* mtan = (bfu16*)alloc((size_t)5 * BT_ * 64 * 2);
  bfu16* xmix0 = (bfu16*)alloc((size_t)5 * BT_ * C_ * 2); // xmix[f] = xmix0 + f*BT*C
  float* rbuf = (float*)alloc((size_t)4 * BT_ * C_ * 4);  // r,k,v,g contiguous
  float* kbuf = rbuf + (size_t)BT_ * C_;
  float* vbuf = kbuf + (size_t)BT_ * C_;
  float* gbuf = vbuf + (size_t)BT_ * C_;
  float* wbuf = (float*)alloc((size_t)BT_ * C_ * 4);
  bfu16* wtan = (bfu16*)alloc((size_t)BT_ * 64 * 2);
  float* Sbuf = (float*)alloc((size_t)64 * 32 * 4096 * 4);  // 32 MB
  float* Gbuf = (float*)alloc((size_t)64 * 32 * 64 * 4);    // 512 KB
  // Aliases (dead-by-then, stream-ordered):
  bfu16* ygb  = xxx;
  float* Ubuf = (float*)(xmix0 + (size_t)1 * BT_ * C_);  // 32MB over xmix[1..4]
  float* part1 = rbuf;   // m-path split-K partials [8][BT][256] (pre-GEMM)
  float* part3 = wbuf;   // w-path split-K partials [8][BT][128] (pre-MODE4)
  float* partW = rbuf;   // Wo K-split partials [4][2048][2048] (post-wkv_c)

  // mtan K-pad must stay zero (pad cols multiply real B rows)
  hipMemsetAsync(mtan, 0, (size_t)5 * BT_ * 64 * 2, stream);

  dim3 tb(256);

  // ---- transposes (f32 -> bf16, [R][C] -> dst[c][r]) ----
  {
    TrP p{}; for (int i = 0; i < 5; ++i) p.src[i] = (const float*)d_in[13 + i];
    p.dst = WT0; p.dStr = (size_t)2048 * 2048; p.R = 2048; p.Cc = 2048; p.Rpad = 2048; p.ldd = 2048;
    transpose_k<<<dim3(64, 64, 5), tb, 0, stream>>>(p);
  }
  {
    TrP p{}; p.src[0] = maa_w1; p.dst = w1T; p.dStr = 0;
    p.R = 2048; p.Cc = 160; p.Rpad = 2048; p.ldd = 2048;
    transpose_k<<<dim3(5, 64, 1), tb, 0, stream>>>(p);
  }
  {
    TrP p{}; p.src[0] = td_w1; p.dst = tw1T; p.dStr = 0;
    p.R = 2048; p.Cc = 64; p.Rpad = 2048; p.ldd = 2048;
    transpose_k<<<dim3(2, 64, 1), tb, 0, stream>>>(p);
  }
  {
    TrP p{}; p.src[0] = td_w2; p.dst = tw2T; p.dStr = 0;
    p.R = 64; p.Cc = 2048; p.Rpad = 64; p.ldd = 64;
    transpose_k<<<dim3(64, 2, 1), tb, 0, stream>>>(p);
  }
  {
    TrP p{}; for (int f = 0; f < 5; ++f) p.src[f] = maa_w2 + (size_t)f * 32 * 2048;
    p.dst = w2T; p.dStr = (size_t)2048 * 64;
    p.R = 32; p.Cc = 2048; p.Rpad = 64; p.ldd = 64;
    transpose_k<<<dim3(64, 2, 5), tb, 0, stream>>>(p);
  }

  // ---- token shift + xxx + xh ----
  prep_xx<<<dim3((BT_ * C_ / 4) / 256), tb, 0, stream>>>(x, maa_x, xxh, xxx, xh);

  // ---- m-path: split-K GEMM (xxx @ maa_w1) ----
  {
    GemmP p{}; p.A = xxx; p.Bt = w1T; p.ldk = 2048; p.kIters = 4; p.kChunk = 256;
    p.ldo = 256; p.pStride = (size_t)BT_ * 256; p.of = part1;
    gemm_k<5><<<dim3(2, 16, 8), tb, 0, stream>>>(p);
  }
  redk_tanh<0><<<dim3(BT_ * 160 / 256), tb, 0, stream>>>(part1, (size_t)BT_ * 256, 256, 160, mtan);

  // ---- token-mix: batched-5 (mtan[f] @ w2T[f]) with xh+xxh epilogue ----
  {
    GemmP p{}; p.A = mtan; p.Bt = w2T; p.ldk = 64; p.kIters = 1;
    p.aStr = (size_t)BT_ * 64; p.bStr = (size_t)2048 * 64; p.oStr = (size_t)BT_ * C_;
    p.ob = xmix0; p.xh = xh; p.xxh = xxh;
    p.vArr[0] = maa_w; p.vArr[1] = maa_k; p.vArr[2] = maa_v; p.vArr[3] = maa_r; p.vArr[4] = maa_g;
    gemm_k<7><<<dim3(16, 16, 5), tb, 0, stream>>>(p);
  }

  // ---- r,k,v,g: batched-4 256^2 swizzled GEMMs ----
  {
    G256P p{}; p.Bt = WT0; p.ldk = 2048; p.nkt = 32; p.kSplit = 1;
    p.bStr = (size_t)2048 * 2048; p.oStr = (size_t)BT_ * C_; p.of = rbuf;
    p.aArr[0] = xmix0 + (size_t)3 * BT_ * C_;  // xr
    p.aArr[1] = xmix0 + (size_t)1 * BT_ * C_;  // xk
    p.aArr[2] = xmix0 + (size_t)2 * BT_ * C_;  // xv
    p.aArr[3] = xmix0 + (size_t)4 * BT_ * C_;  // xg
    gemm256<<<dim3(8, 8, 4), dim3(512), 131072, stream>>>(p);
  }

  // ---- w-path: split-K thin GEMM (xw @ td_w1) ----
  {
    GemmP p{}; p.A = xmix0; p.Bt = tw1T; p.ldk = 2048; p.kIters = 4; p.kChunk = 256;
    p.ldo = 128; p.pStride = (size_t)BT_ * 128; p.of = part3;
    gemm_k<5><<<dim3(1, 16, 8), tb, 0, stream>>>(p);
  }
  redk_tanh<1><<<dim3(BT_ * 64 / 256), tb, 0, stream>>>(part3, (size_t)BT_ * 128, 128, 64, wtan);

  // ---- w-path: wbuf = lw = -exp(tdec + wtan @ td_w2)  (fused) ----
  {
    GemmP p{}; p.A = wtan; p.Bt = tw2T; p.ldk = 64; p.kIters = 1;
    p.of = wbuf; p.ldo = 2048; p.vArr[0] = tdec;
    gemm_k<4><<<dim3(16, 16, 1), tb, 0, stream>>>(p);
  }

  // ---- chunked WKV6 (L=32) ----
  wkv_a32<<<dim3(2048), tb, 0, stream>>>(rbuf, kbuf, vbuf, wbuf, u, rbuf, ybuf, Ubuf, Gbuf);
  wkv_b32<<<dim3(64),   tb, 0, stream>>>(Ubuf, Gbuf, Sbuf);
  wkv_c32<<<dim3(2048), tb, 0, stream>>>(rbuf, Sbuf, ybuf);

  // ---- GroupNorm * silu(g) ----
  gnorm_kernel<<<dim3(BT_), tb, 0, stream>>>(ybuf, gbuf, lng, lnb, ygb);

  // ---- out = yg @ Wo  (256^2 swizzled, K-split 4 -> partials -> sum) ----
  {
    G256P p{}; p.Bt = WT0 + (size_t)4 * 2048 * 2048; p.ldk = 2048;
    p.nkt = 8; p.kSplit = 4;
    p.bStr = 0; p.oStr = (size_t)2048 * 2048; p.of = partW;
    p.aArr[0] = ygb;
    gemm256<<<dim3(8, 8, 4), dim3(512), 131072, stream>>>(p);
  }
  redk_sum4<<<dim3(4096), tb, 0, stream>>>(partW, out);
}

// Round 9
// 317.127 us; speedup vs baseline: 1.0966x; 1.0966x over previous
//
#include <hip/hip_runtime.h>
#include <cstdint>
#include <cstddef>

// Problem constants (fixed by the reference)
#define B_  2
#define T_  1024
#define C_  2048
#define H_  32
#define BT_ (B_*T_)
static constexpr float EPS_GN = 1e-5f * 64.0f;

using short8 = __attribute__((ext_vector_type(8))) short;
using f32x4  = __attribute__((ext_vector_type(4))) float;
typedef unsigned short bfu16;

__device__ __forceinline__ bfu16 f2b(float f) {
  uint32_t x = __float_as_uint(f);
  uint32_t r = (x + 0x7FFFu + ((x >> 16) & 1u)) >> 16;
  return (bfu16)r;
}
__device__ __forceinline__ float b2f(bfu16 h) {
  return __uint_as_float(((uint32_t)h) << 16);
}

__device__ __forceinline__ void gload16(const bfu16* g, bfu16* l) {
  __builtin_amdgcn_global_load_lds((__attribute__((address_space(1))) void*)g,
                                   (__attribute__((address_space(3))) void*)l,
                                   16, 0, 0);
}

// ---------------------------------------------------------------------------
// gemm256 (round-7 proven schedule, frozen): 256x256 tile, BK=64, 512 thr
// (8 waves 2Mx4N), dbuf LDS 128KB. STAGE_A(next); vmcnt(4); barrier; per-ks
// {STAGE_B(next) at ks==1; ds_read frags; MFMA}; barrier.
// LDS XOR-swizzle: source col ^((row&7)<<3), read col ^((lane&7)<<3).
// XCD-aware bijective block swizzle (nwg % 8 == 0 required).
// kSplit==1: batched over z (A=aArr[z], Bt+=z*bStr, out+=z*oStr).
// kSplit>1 : z = K-chunk of A/Bt (out+=z*oStr, f32 partials).
// ---------------------------------------------------------------------------
struct G256P {
  const bfu16* Bt; float* of;
  size_t bStr, oStr;
  int ldk, nkt, kSplit;
  const bfu16* aArr[4];
};

__global__ __launch_bounds__(512, 2)
void gemm256(G256P p)
{
  extern __shared__ __align__(16) bfu16 sm[];   // A0,A1,B0,B1 each 256*64
  const int tid  = threadIdx.x;
  const int nwg = gridDim.x * gridDim.y * gridDim.z;
  int lin = blockIdx.x + gridDim.x * (blockIdx.y + gridDim.y * blockIdx.z);
  lin = (lin & 7) * (nwg >> 3) + (lin >> 3);
  const int bx = lin % gridDim.x;
  const int by = (lin / gridDim.x) % gridDim.y;
  const int z  = lin / (gridDim.x * gridDim.y);
  const int m0   = by * 256, n0 = bx * 256;
  const int lane = tid & 63;
  const int wv   = tid >> 6;
  const int wm   = wv >> 2, wn = wv & 3;
  const int ldk  = p.ldk;

  const bfu16* A;
  size_t koff;
  if (p.kSplit > 1) { A = p.aArr[0]; koff = (size_t)z * p.nkt * 64; }
  else              { A = p.aArr[z]; koff = 0; }
  const bfu16* Bt = p.Bt + (size_t)z * p.bStr;

  const int srow = tid >> 3;        // 0..63
  const int scol = (tid & 7) * 8;   // 0..56
  const int sswz = (srow & 7) << 3; // source-side inverse swizzle
  const bfu16* gA = A  + (size_t)(m0 + srow) * ldk + koff + (scol ^ sswz);
  const bfu16* gB = Bt + (size_t)(n0 + srow) * ldk + koff + (scol ^ sswz);

  auto STAGE_A = [&](bfu16* dst, int kt) {
    const bfu16* g = gA + (size_t)kt * 64;
    bfu16* l = dst + srow * 64 + scol;
#pragma unroll
    for (int it = 0; it < 4; ++it)
      gload16(g + (size_t)it * 64 * ldk, l + it * 4096);
  };
  auto STAGE_B = [&](bfu16* dst, int kt) {
    const bfu16* g = gB + (size_t)kt * 64;
    bfu16* l = dst + srow * 64 + scol;
#pragma unroll
    for (int it = 0; it < 4; ++it)
      gload16(g + (size_t)it * 64 * ldk, l + it * 4096);
  };

  f32x4 acc[8][4];
  const f32x4 zero = {0.f, 0.f, 0.f, 0.f};
#pragma unroll
  for (int i = 0; i < 8; ++i)
#pragma unroll
    for (int j = 0; j < 4; ++j) acc[i][j] = zero;

  STAGE_A(sm, 0);
  STAGE_B(sm + 32768, 0);           // 8 outstanding

  const int rswz = (lane & 7) << 3; // read-side swizzle

  for (int kt = 0; kt < p.nkt; ++kt) {
    bfu16* curA = sm + (kt & 1) * 16384;
    bfu16* curB = sm + 32768 + (kt & 1) * 16384;
    bfu16* nxtA = sm + ((kt & 1) ^ 1) * 16384;
    bfu16* nxtB = sm + 32768 + ((kt & 1) ^ 1) * 16384;
    const bool more = (kt + 1 < p.nkt);
    if (more) {
      STAGE_A(nxtA, kt + 1);                       // 12 outstanding
      asm volatile("s_waitcnt vmcnt(4)" ::: "memory");  // cur buf landed
    } else {
      asm volatile("s_waitcnt vmcnt(0)" ::: "memory");
    }
    __builtin_amdgcn_s_barrier();

#pragma unroll
    for (int ks = 0; ks < 2; ++ks) {
      if (ks == 1 && more) STAGE_B(nxtB, kt + 1);
      const int ko = (ks * 32 + (lane >> 4) * 8) ^ rswz;
      short8 a[8], b[4];
#pragma unroll
      for (int i = 0; i < 8; ++i)
        a[i] = *(const short8*)(curA + (wm * 128 + i * 16 + (lane & 15)) * 64 + ko);
#pragma unroll
      for (int j = 0; j < 4; ++j)
        b[j] = *(const short8*)(curB + (wn * 64 + j * 16 + (lane & 15)) * 64 + ko);
      __builtin_amdgcn_s_setprio(1);
#pragma unroll
      for (int i = 0; i < 8; ++i)
#pragma unroll
        for (int j = 0; j < 4; ++j)
          acc[i][j] = __builtin_amdgcn_mfma_f32_16x16x32_bf16(a[i], b[j], acc[i][j], 0, 0, 0);
      __builtin_amdgcn_s_setprio(0);
    }
    __builtin_amdgcn_s_barrier();
  }

  float* o = p.of + (size_t)z * p.oStr;
  const int cb = n0 + wn * 64 + (lane & 15);
  const int rb = m0 + wm * 128 + ((lane >> 4) << 2);
#pragma unroll
  for (int i = 0; i < 8; ++i)
#pragma unroll
    for (int j = 0; j < 4; ++j) {
      int col = cb + j * 16;
#pragma unroll
      for (int q = 0; q < 4; ++q)
        o[(size_t)(rb + i * 16 + q) * 2048 + col] = acc[i][j][q];
    }
}

// ---------------------------------------------------------------------------
// 128x128 GEMM for the small/odd shapes.
// MODE 4: of = -exp(vArr[0][col] + acc)   (fused lw = -exp(w))
// MODE 5: split-K partials
// MODE 7: batched-5 token-mix epilogue (x and xx both bf16)
// ---------------------------------------------------------------------------
struct GemmP {
  const bfu16* A; const bfu16* Bt;
  float* of; bfu16* ob;
  const bfu16* xh; const bfu16* xxh;
  int ldk, kIters, kChunk, ldo;
  size_t pStride, aStr, bStr, oStr;
  const float* vArr[5];
};

template<int MODE>
__global__ __launch_bounds__(256)
void gemm_k(GemmP p)
{
  __shared__ alignas(16) bfu16 As[128*64];
  __shared__ alignas(16) bfu16 Bs[128*64];
  const int tid  = threadIdx.x;
  const int z    = blockIdx.z;
  const int m0   = blockIdx.y * 128, n0 = blockIdx.x * 128;
  const int lane = tid & 63;
  const int wv   = tid >> 6;
  const int wr   = (wv >> 1) * 64, wc = (wv & 1) * 64;

  const bfu16* A  = p.A;
  const bfu16* Bt = p.Bt;
  size_t koff = 0;
  if constexpr (MODE == 7) { A += (size_t)z * p.aStr; Bt += (size_t)z * p.bStr; }
  if constexpr (MODE == 5) { koff = (size_t)z * p.kChunk; }

  f32x4 acc[4][4];
  const f32x4 zero = {0.f, 0.f, 0.f, 0.f};
#pragma unroll
  for (int i = 0; i < 4; ++i)
#pragma unroll
    for (int j = 0; j < 4; ++j) acc[i][j] = zero;

  const int srow = tid >> 3;
  const int scol = (tid & 7) * 8;
  const int ldk  = p.ldk;

  for (int kb = 0; kb < p.kIters; ++kb) {
    const bfu16* ga = A  + (size_t)m0 * ldk + koff + kb * 64;
    const bfu16* gb = Bt + (size_t)n0 * ldk + koff + kb * 64;
#pragma unroll
    for (int it = 0; it < 4; ++it) {
      int r = it * 32 + srow;
      gload16(ga + (size_t)r * ldk + scol, As + r * 64 + scol);
      gload16(gb + (size_t)r * ldk + scol, Bs + r * 64 + scol);
    }
    __syncthreads();
#pragma unroll
    for (int kk = 0; kk < 2; ++kk) {
      const int ko = kk * 32 + (lane >> 4) * 8;
      short8 a[4], b[4];
#pragma unroll
      for (int i = 0; i < 4; ++i)
        a[i] = *(const short8*)(As + (wr + i * 16 + (lane & 15)) * 64 + ko);
#pragma unroll
      for (int j = 0; j < 4; ++j)
        b[j] = *(const short8*)(Bs + (wc + j * 16 + (lane & 15)) * 64 + ko);
#pragma unroll
      for (int i = 0; i < 4; ++i)
#pragma unroll
        for (int j = 0; j < 4; ++j)
          acc[i][j] = __builtin_amdgcn_mfma_f32_16x16x32_bf16(a[i], b[j], acc[i][j], 0, 0, 0);
    }
    __syncthreads();
  }

  const int cb = n0 + wc + (lane & 15);
  const int rb = m0 + wr + ((lane >> 4) << 2);
#pragma unroll
  for (int i = 0; i < 4; ++i) {
#pragma unroll
    for (int j = 0; j < 4; ++j) {
      int col = cb + j * 16;
#pragma unroll
      for (int q = 0; q < 4; ++q) {
        int row = rb + i * 16 + q;
        float v = acc[i][j][q];
        if constexpr (MODE == 4) {
          p.of[(size_t)row * p.ldo + col] = -__expf(p.vArr[0][col] + v);
        } else if constexpr (MODE == 5) {
          p.of[(size_t)z * p.pStride + (size_t)row * p.ldo + col] = v;
        } else if constexpr (MODE == 7) {
          size_t idx = (size_t)row * C_ + col;
          (p.ob + (size_t)z * p.oStr)[idx] =
              f2b(b2f(p.xh[idx]) + b2f(p.xxh[idx]) * (p.vArr[z][col] + v));
        }
      }
    }
  }
}

// ---------------------------------------------------------------------------
// split-K reduce + tanh -> bf16.  OUT=0: mtan scatter [f][row][d]; OUT=1: wtan.
// NS = number of K-chunks to sum.
// ---------------------------------------------------------------------------
template<int OUT, int NS>
__global__ __launch_bounds__(256)
void redk_tanh(const float* __restrict__ part, size_t pStr, int ldo, int ncols,
               bfu16* __restrict__ out)
{
  int id = blockIdx.x * 256 + threadIdx.x;
  int row = id / ncols, col = id % ncols;
  if (row >= BT_) return;
  float v = 0.f;
#pragma unroll
  for (int s = 0; s < NS; ++s) v += part[(size_t)s * pStr + (size_t)row * ldo + col];
  bfu16 tv = f2b(tanhf(v));
  if constexpr (OUT == 0)
    out[((size_t)(col >> 5) * BT_ + row) * 64 + (col & 31)] = tv;
  else
    out[(size_t)row * 64 + col] = tv;
}

__global__ __launch_bounds__(256)
void redk_sum4(const float* __restrict__ p0, float* __restrict__ out)
{
  size_t i = ((size_t)blockIdx.x * 256 + threadIdx.x) * 4;
  const size_t str = (size_t)2048 * 2048;
  float4 a = *(const float4*)(p0 + i);
  float4 b = *(const float4*)(p0 + str + i);
  float4 c = *(const float4*)(p0 + 2 * str + i);
  float4 d = *(const float4*)(p0 + 3 * str + i);
  a.x += b.x + c.x + d.x; a.y += b.y + c.y + d.y;
  a.z += b.z + c.z + d.z; a.w += b.w + c.w + d.w;
  *(float4*)(out + i) = a;
}

// ---------------------------------------------------------------------------
// f32 [R][Cc] -> bf16 dst[c*ldd + r], batched over z. Rows [R,Rpad) zeroed.
// ---------------------------------------------------------------------------
struct TrP { const float* src[5]; bfu16* dst; size_t dStr; int R, Cc, Rpad, ldd; };

__global__ __launch_bounds__(256)
void transpose_k(TrP p)
{
  __shared__ float tile[32][33];
  const float* src = p.src[blockIdx.z];
  bfu16* dst = p.dst + (size_t)blockIdx.z * p.dStr;
  const int tx = threadIdx.x & 31, ty = threadIdx.x >> 5;
  const int r0 = blockIdx.y * 32, c0 = blockIdx.x * 32;
#pragma unroll
  for (int i = 0; i < 4; ++i) {
    int r = r0 + ty + i * 8, c = c0 + tx;
    tile[ty + i * 8][tx] = (r < p.R && c < p.Cc) ? src[(size_t)r * p.Cc + c] : 0.f;
  }
  __syncthreads();
#pragma unroll
  for (int i = 0; i < 4; ++i) {
    int c = c0 + ty + i * 8, r = r0 + tx;
    if (c < p.Cc && r < p.Rpad) dst[(size_t)c * p.ldd + r] = f2b(tile[tx][ty + i * 8]);
  }
}

// ---------------------------------------------------------------------------
// xx = shift(x) - x (bf16) ; xxx = bf16(x + xx*maa_x) ; xh = bf16(x)
// ---------------------------------------------------------------------------
__global__ __launch_bounds__(256)
void prep_xx(const float* __restrict__ x, const float* __restrict__ maa_x,
             bfu16* __restrict__ xxh, bfu16* __restrict__ xxx,
             bfu16* __restrict__ xh)
{
  size_t i = ((size_t)blockIdx.x * 256 + threadIdx.x) * 4;
  int c  = (int)(i & (C_ - 1));
  int bt = (int)(i >> 11);
  int t  = bt & (T_ - 1);
  float4 xv = *(const float4*)(x + i);
  float4 xp = {0.f, 0.f, 0.f, 0.f};
  if (t > 0) xp = *(const float4*)(x + i - C_);
  float4 mx = *(const float4*)(maa_x + c);
  float dx = xp.x - xv.x, dy = xp.y - xv.y, dz = xp.z - xv.z, dw = xp.w - xv.w;
  uint2 w0;
  w0.x = (uint32_t)f2b(dx) | ((uint32_t)f2b(dy) << 16);
  w0.y = (uint32_t)f2b(dz) | ((uint32_t)f2b(dw) << 16);
  *(uint2*)(xxh + i) = w0;
  uint2 w1;
  w1.x = (uint32_t)f2b(xv.x + dx * mx.x) | ((uint32_t)f2b(xv.y + dy * mx.y) << 16);
  w1.y = (uint32_t)f2b(xv.z + dz * mx.z) | ((uint32_t)f2b(xv.w + dw * mx.w) << 16);
  *(uint2*)(xxx + i) = w1;
  uint2 w2;
  w2.x = (uint32_t)f2b(xv.x) | ((uint32_t)f2b(xv.y) << 16);
  w2.y = (uint32_t)f2b(xv.z) | ((uint32_t)f2b(xv.w) << 16);
  *(uint2*)(xh + i) = w2;
}

// ---------------------------------------------------------------------------
// WKV6 chunked scan, chunk L=32. w input is ALREADY lw = -exp(w).
// ---------------------------------------------------------------------------
#define S32 68   // LDS row stride (floats) for 32-row tiles

__global__ __launch_bounds__(256)
void wkv_a32(const float* __restrict__ r, const float* __restrict__ k,
             const float* __restrict__ v, const float* __restrict__ w,
             const float* __restrict__ u, float* __restrict__ rp,
             float* __restrict__ y, float* __restrict__ U, float* __restrict__ G)
{
  __shared__ float rw[32 * S32];
  __shared__ float kk[32 * S32];
  __shared__ float vv[32 * S32];
  __shared__ float Ps[32 * S32];
  __shared__ float red[256];
  __shared__ float diag[32];
  __shared__ float Gl[64];

  const int blk = blockIdx.x;
  const int bh = blk >> 5, c = blk & 31;
  const int b = bh >> 5, h = bh & 31;
  const int tid = threadIdx.x;
  const size_t gbase = ((size_t)(b * T_ + c * 32)) * C_ + h * 64;

  {
    const int t = tid >> 3, q = tid & 7;
    const size_t g = gbase + (size_t)t * C_ + q * 8;
    const int l = t * S32 + q * 8;
    *(float4*)(rw + l)     = *(const float4*)(r + g);
    *(float4*)(rw + l + 4) = *(const float4*)(r + g + 4);
    *(float4*)(kk + l)     = *(const float4*)(k + g);
    *(float4*)(kk + l + 4) = *(const float4*)(k + g + 4);
    *(float4*)(vv + l)     = *(const float4*)(v + g);
    *(float4*)(vv + l + 4) = *(const float4*)(v + g + 4);
    *(float4*)(Ps + l)     = *(const float4*)(w + g);
    *(float4*)(Ps + l + 4) = *(const float4*)(w + g + 4);
  }
  __syncthreads();

  // segmented prefix over t (4 segments of 8), per-j
  {
    const int seg = tid >> 6, j = tid & 63;
    float loc = 0.f;
#pragma unroll
    for (int tt = 0; tt < 8; ++tt) loc += Ps[(seg * 8 + tt) * S32 + j];
    red[seg * 64 + j] = loc;
  }
  __syncthreads();
  {
    const int seg = tid >> 6, j = tid & 63;
    float cs = 0.f;
    for (int s = 0; s < seg; ++s) cs += red[s * 64 + j];
    const float uj = u[h * 64 + j];
#pragma unroll
    for (int tt = 0; tt < 8; ++tt) {
      const int a = (seg * 8 + tt) * S32 + j;
      float lw = Ps[a];
      float rv = rw[a] * __expf(cs);
      rw[a] = rv;
      cs += lw;
      float kv = kk[a] * __expf(-cs);
      kk[a] = kv;
      Ps[a] = rv * kv * uj * __expf(lw);   // D (exact)
    }
    if (seg == 3) {
      float Gj = __expf(cs);
      Gl[j] = Gj;
      G[((size_t)bh * 32 + c) * 64 + j] = Gj;
    }
  }
  __syncthreads();

  // diag[t] = sum_j D[t][j]
  {
    const int t = tid & 31, q = tid >> 5;
    float s = 0.f;
#pragma unroll
    for (int jj = 0; jj < 8; ++jj) s += Ps[t * S32 + q * 8 + jj];
    red[q * 32 + t] = s;
  }
  __syncthreads();
  if (tid < 32) {
    float d = 0.f;
#pragma unroll
    for (int q = 0; q < 8; ++q) d += red[q * 32 + tid];
    diag[tid] = d;
  }
  __syncthreads();

  // scores: 2x2 tiles over 16x16 thread grid, lower-tri
  {
    const int tq = tid >> 4, sq = tid & 15;
    float a00 = 0.f, a01 = 0.f, a10 = 0.f, a11 = 0.f;
    if (sq <= tq) {
      for (int j = 0; j < 64; j += 4) {
        float4 r0 = *(const float4*)(rw + (2 * tq + 0) * S32 + j);
        float4 r1 = *(const float4*)(rw + (2 * tq + 1) * S32 + j);
        float4 k0 = *(const float4*)(kk + (2 * sq + 0) * S32 + j);
        float4 k1 = *(const float4*)(kk + (2 * sq + 1) * S32 + j);
        a00 += r0.x * k0.x + r0.y * k0.y + r0.z * k0.z + r0.w * k0.w;
        a01 += r0.x * k1.x + r0.y * k1.y + r0.z * k1.z + r0.w * k1.w;
        a10 += r1.x * k0.x + r1.y * k0.y + r1.z * k0.z + r1.w * k0.w;
        a11 += r1.x * k1.x + r1.y * k1.y + r1.z * k1.z + r1.w * k1.w;
      }
    }
    __syncthreads();
    if (sq <= tq) {
      const float av[2][2] = {{a00, a01}, {a10, a11}};
#pragma unroll
      for (int tt = 0; tt < 2; ++tt)
#pragma unroll
        for (int ss = 0; ss < 2; ++ss) {
          int t = 2 * tq + tt, s = 2 * sq + ss;
          Ps[t * S32 + s] = (s < t) ? av[tt][ss] : (s == t ? diag[t] : 0.f);
        }
    }
  }
  __syncthreads();

  // O_intra[t][i] = sum_{s<=t} P[t][s] * v[s][i]  -> y
  {
    const int tq = tid >> 4, iq = tid & 15;
    float o0[4] = {0.f, 0.f, 0.f, 0.f}, o1[4] = {0.f, 0.f, 0.f, 0.f};
    const int tmax = 2 * tq + 1;
    for (int s = 0; s <= tmax; ++s) {
      float4 vx = *(const float4*)(vv + s * S32 + iq * 4);
      float p0 = Ps[(2 * tq + 0) * S32 + s];
      float p1 = Ps[(2 * tq + 1) * S32 + s];
      o0[0] += p0 * vx.x; o0[1] += p0 * vx.y; o0[2] += p0 * vx.z; o0[3] += p0 * vx.w;
      o1[0] += p1 * vx.x; o1[1] += p1 * vx.y; o1[2] += p1 * vx.z; o1[3] += p1 * vx.w;
    }
    float4 w0 = {o0[0], o0[1], o0[2], o0[3]};
    float4 w1 = {o1[0], o1[1], o1[2], o1[3]};
    *(float4*)(y + gbase + (size_t)(2 * tq + 0) * C_ + iq * 4) = w0;
    *(float4*)(y + gbase + (size_t)(2 * tq + 1) * C_ + iq * 4) = w1;
  }

  // U[j][i] = G[j] * sum_s k~[s][j] * v[s][i]
  {
    const int jq = tid >> 4, iq = tid & 15;
    float ua[4][4] = {{0.f}};
    for (int s = 0; s < 32; ++s) {
      float4 kx = *(const float4*)(kk + s * S32 + jq * 4);
      float4 vx = *(const float4*)(vv + s * S32 + iq * 4);
      ua[0][0] += kx.x * vx.x; ua[0][1] += kx.x * vx.y; ua[0][2] += kx.x * vx.z; ua[0][3] += kx.x * vx.w;
      ua[1][0] += kx.y * vx.x; ua[1][1] += kx.y * vx.y; ua[1][2] += kx.y * vx.z; ua[1][3] += kx.y * vx.w;
      ua[2][0] += kx.z * vx.x; ua[2][1] += kx.z * vx.y; ua[2][2] += kx.z * vx.z; ua[2][3] += kx.z * vx.w;
      ua[3][0] += kx.w * vx.x; ua[3][1] += kx.w * vx.y; ua[3][2] += kx.w * vx.z; ua[3][3] += kx.w * vx.w;
    }
    const size_t ub = ((size_t)bh * 32 + c) * 4096;
#pragma unroll
    for (int jj = 0; jj < 4; ++jj) {
      float g = Gl[jq * 4 + jj];
      float4 uv = {ua[jj][0] * g, ua[jj][1] * g, ua[jj][2] * g, ua[jj][3] * g};
      *(float4*)(U + ub + (size_t)(jq * 4 + jj) * 64 + iq * 4) = uv;
    }
  }

  // write r' back (for phase C)
  {
    const int t = tid >> 3, q = tid & 7;
    const size_t g = gbase + (size_t)t * C_ + q * 8;
    const int l = t * S32 + q * 8;
    *(float4*)(rp + g)     = *(const float4*)(rw + l);
    *(float4*)(rp + g + 4) = *(const float4*)(rw + l + 4);
  }
}

// ---------------------------------------------------------------------------
// State scan: S_{c+1} = G_c*S_c + U_c. Independent per (j,i) -> 256 blocks
// (bh x j-quarter), one float4 of i per thread, no LDS, no barriers.
// ---------------------------------------------------------------------------
__global__ __launch_bounds__(256)
void wkv_b32(const float* __restrict__ U, const float* __restrict__ G,
             float* __restrict__ Sbuf)
{
  const int bh = blockIdx.x >> 2, jq = blockIdx.x & 3;
  const int tid = threadIdx.x;
  const int j = jq * 16 + (tid >> 4);
  const int i = (tid & 15) * 4;
  float4 S = {0.f, 0.f, 0.f, 0.f};
  for (int c = 0; c < 32; ++c) {
    const size_t cb = ((size_t)bh * 32 + c);
    float g = G[cb * 64 + j];
    const size_t idx = cb * 4096 + (size_t)j * 64 + i;
    *(float4*)(Sbuf + idx) = S;
    float4 uv = *(const float4*)(U + idx);
    S.x = g * S.x + uv.x; S.y = g * S.y + uv.y;
    S.z = g * S.z + uv.z; S.w = g * S.w + uv.w;
  }
}

// ---------------------------------------------------------------------------
// Phase C + fused GroupNorm*silu(g) -> bf16 ygb.
// y_final = y_intra + r' @ S_chunkstart; per-row (64-ch head group) norm via
// 16-lane shfl reduce; multiply silu(gpre); write bf16.
// ---------------------------------------------------------------------------
__global__ __launch_bounds__(256)
void wkv_c32(const float* __restrict__ rp, const float* __restrict__ Sbuf,
             const float* __restrict__ y, const float* __restrict__ gpre,
             const float* __restrict__ lng, const float* __restrict__ lnb,
             bfu16* __restrict__ yg)
{
  __shared__ float Sl[64 * S32];
  __shared__ float rl[32 * S32];
  const int blk = blockIdx.x;
  const int bh = blk >> 5, c = blk & 31;
  const int b = bh >> 5, h = bh & 31;
  const int tid = threadIdx.x;
  const size_t gbase = ((size_t)(b * T_ + c * 32)) * C_ + h * 64;
  {
    const int j = tid >> 2, q = tid & 3;     // S: 64 rows x 64 cols
    const size_t sb = ((size_t)bh * 32 + c) * 4096 + (size_t)j * 64 + q * 16;
    const int l = j * S32 + q * 16;
#pragma unroll
    for (int p = 0; p < 4; ++p)
      *(float4*)(Sl + l + p * 4) = *(const float4*)(Sbuf + sb + p * 4);
    const int t = tid >> 3, q8 = tid & 7;    // r': 32 rows x 64 cols
    const size_t gr = gbase + (size_t)t * C_ + q8 * 8;
    const int lr = t * S32 + q8 * 8;
    *(float4*)(rl + lr)     = *(const float4*)(rp + gr);
    *(float4*)(rl + lr + 4) = *(const float4*)(rp + gr + 4);
  }
  __syncthreads();
  const int tq = tid >> 4, iq = tid & 15;
  float o0[4] = {0.f, 0.f, 0.f, 0.f}, o1[4] = {0.f, 0.f, 0.f, 0.f};
  for (int j = 0; j < 64; ++j) {
    float4 sv = *(const float4*)(Sl + j * S32 + iq * 4);
    float r0 = rl[(2 * tq + 0) * S32 + j];
    float r1 = rl[(2 * tq + 1) * S32 + j];
    o0[0] += r0 * sv.x; o0[1] += r0 * sv.y; o0[2] += r0 * sv.z; o0[3] += r0 * sv.w;
    o1[0] += r1 * sv.x; o1[1] += r1 * sv.y; o1[2] += r1 * sv.z; o1[3] += r1 * sv.w;
  }
  // finalize two rows with fused GroupNorm * silu(gpre)
#pragma unroll
  for (int rr = 0; rr < 2; ++rr) {
    float* o = rr ? o1 : o0;
    const size_t rowb = gbase + (size_t)(2 * tq + rr) * C_;
    float4 yi = *(const float4*)(y + rowb + iq * 4);
    float yv[4] = {yi.x + o[0], yi.y + o[1], yi.z + o[2], yi.w + o[3]};
    float s = yv[0] + yv[1] + yv[2] + yv[3];
    float sq = yv[0] * yv[0] + yv[1] * yv[1] + yv[2] * yv[2] + yv[3] * yv[3];
#pragma unroll
    for (int m = 1; m < 16; m <<= 1) {
      s  += __shfl_xor(s, m, 64);
      sq += __shfl_xor(sq, m, 64);
    }
    float mu  = s * (1.f / 64.f);
    float var = sq * (1.f / 64.f) - mu * mu;
    float rs  = rsqrtf(var + EPS_GN);
    float4 gp = *(const float4*)(gpre + rowb + iq * 4);
    const float gpv[4] = {gp.x, gp.y, gp.z, gp.w};
    uint32_t pk[2];
    ushort hw[4];
#pragma unroll
    for (int e = 0; e < 4; ++e) {
      int cidx = h * 64 + iq * 4 + e;
      float yn = (yv[e] - mu) * rs * lng[cidx] + lnb[cidx];
      float gs = gpv[e] / (1.f + __expf(-gpv[e]));
      hw[e] = f2b(yn * gs);
    }
    pk[0] = (uint32_t)hw[0] | ((uint32_t)hw[1] << 16);
    pk[1] = (uint32_t)hw[2] | ((uint32_t)hw[3] << 16);
    *(uint2*)(yg + rowb + iq * 4) = make_uint2(pk[0], pk[1]);
  }
}

// ---------------------------------------------------------------------------
extern "C" void kernel_launch(void* const* d_in, const int* in_sizes, int n_in,
                              void* d_out, int out_size, void* d_ws, size_t ws_size,
                              hipStream_t stream)
{
  const float* x      = (const float*)d_in[0];
  const float* maa_x  = (const float*)d_in[1];
  const float* maa_w  = (const float*)d_in[2];
  const float* maa_k  = (const float*)d_in[3];
  const float* maa_v  = (const float*)d_in[4];
  const float* maa_r  = (const float*)d_in[5];
  const float* maa_g  = (const float*)d_in[6];
  const float* tdec   = (const float*)d_in[7];
  const float* u      = (const float*)d_in[8];
  const float* maa_w1 = (const float*)d_in[9];
  const float* maa_w2 = (const float*)d_in[10];
  const float* td_w1  = (const float*)d_in[11];
  const float* td_w2  = (const float*)d_in[12];
  const float* lng = (const float*)d_in[18];
  const float* lnb = (const float*)d_in[19];
  float* out = (float*)d_out;

  char* wsp = (char*)d_ws;
  auto alloc = [&](size_t bytes) -> char* {
    char* p = wsp;
    wsp += (bytes + 255) & ~(size_t)255;
    return p;
  };

  bfu16* WT0 = (bfu16*)alloc((size_t)5 * 2048 * 2048 * 2);  // WT[z] = WT0 + z*4M
  bfu16* w1T  = (bfu16*)alloc((size_t)256 * 2048 * 2);
  bfu16* tw1T = (bfu16*)alloc((size_t)128 * 2048 * 2);
  bfu16* tw2T = (bfu16*)alloc((size_t)2048 * 64 * 2);
  bfu16* w2T  = (bfu16*)alloc((size_t)5 * 2048 * 64 * 2);
  float* ybuf = (float*)alloc((size_t)BT_ * C_ * 4);
  bfu16* xxh  = (bfu16*)alloc((size_t)BT_ * C_ * 2);
  bfu16* xxx  = (bfu16*)alloc((size_t)BT_ * C_ * 2);
  bfu16* xh   = (bfu16*)alloc((size_t)BT_ * C_ * 2);
  bfu16* mtan = (bfu16*)alloc((size_t)5 * BT_ * 64 * 2);
  bfu16* xmix0 = (bfu16*)alloc((size_t)5 * BT_ * C_ * 2); // xmix[f] = xmix0 + f*BT*C
  float* rbuf = (float*)alloc((size_t)4 * BT_ * C_ * 4);  // r,k,v,g contiguous
  float* kbuf = rbuf + (size_t)BT_ * C_;
  float* vbuf = kbuf + (size_t)BT_ * C_;
  float* gbuf = vbuf + (size_t)BT_ * C_;
  float* wbuf = (float*)alloc((size_t)BT_ * C_ * 4);
  bfu16* wtan = (bfu16*)alloc((size_t)BT_ * 64 * 2);
  float* Sbuf = (float*)alloc((size_t)64 * 32 * 4096 * 4);  // 32 MB
  float* Gbuf = (float*)alloc((size_t)64 * 32 * 64 * 4);    // 512 KB
  // Aliases (dead-by-then, stream-ordered):
  bfu16* ygb  = xxx;
  float* Ubuf = (float*)(xmix0 + (size_t)1 * BT_ * C_);  // 32MB over xmix[1..4]
  float* part1 = rbuf;   // m-path split-K partials [8][BT][256] (pre-GEMM)
  float* part3 = wbuf;   // w-path split-K partials [16][BT][128] (pre-MODE4)
  float* partW = rbuf;   // Wo K-split partials [4][2048][2048] (post-wkv_c)

  // mtan K-pad must stay zero (pad cols multiply real B rows)
  hipMemsetAsync(mtan, 0, (size_t)5 * BT_ * 64 * 2, stream);

  dim3 tb(256);

  // ---- transposes (f32 -> bf16, [R][C] -> dst[c][r]) ----
  {
    TrP p{}; for (int i = 0; i < 5; ++i) p.src[i] = (const float*)d_in[13 + i];
    p.dst = WT0; p.dStr = (size_t)2048 * 2048; p.R = 2048; p.Cc = 2048; p.Rpad = 2048; p.ldd = 2048;
    transpose_k<<<dim3(64, 64, 5), tb, 0, stream>>>(p);
  }
  {
    TrP p{}; p.src[0] = maa_w1; p.dst = w1T; p.dStr = 0;
    p.R = 2048; p.Cc = 160; p.Rpad = 2048; p.ldd = 2048;
    transpose_k<<<dim3(5, 64, 1), tb, 0, stream>>>(p);
  }
  {
    TrP p{}; p.src[0] = td_w1; p.dst = tw1T; p.dStr = 0;
    p.R = 2048; p.Cc = 64; p.Rpad = 2048; p.ldd = 2048;
    transpose_k<<<dim3(2, 64, 1), tb, 0, stream>>>(p);
  }
  {
    TrP p{}; p.src[0] = td_w2; p.dst = tw2T; p.dStr = 0;
    p.R = 64; p.Cc = 2048; p.Rpad = 64; p.ldd = 64;
    transpose_k<<<dim3(64, 2, 1), tb, 0, stream>>>(p);
  }
  {
    TrP p{}; for (int f = 0; f < 5; ++f) p.src[f] = maa_w2 + (size_t)f * 32 * 2048;
    p.dst = w2T; p.dStr = (size_t)2048 * 64;
    p.R = 32; p.Cc = 2048; p.Rpad = 64; p.ldd = 64;
    transpose_k<<<dim3(64, 2, 5), tb, 0, stream>>>(p);
  }

  // ---- token shift + xxx + xh ----
  prep_xx<<<dim3((BT_ * C_ / 4) / 256), tb, 0, stream>>>(x, maa_x, xxh, xxx, xh);

  // ---- m-path: split-K GEMM (xxx @ maa_w1) ----
  {
    GemmP p{}; p.A = xxx; p.Bt = w1T; p.ldk = 2048; p.kIters = 4; p.kChunk = 256;
    p.ldo = 256; p.pStride = (size_t)BT_ * 256; p.of = part1;
    gemm_k<5><<<dim3(2, 16, 8), tb, 0, stream>>>(p);
  }
  redk_tanh<0, 8><<<dim3(BT_ * 160 / 256), tb, 0, stream>>>(part1, (size_t)BT_ * 256, 256, 160, mtan);

  // ---- token-mix: batched-5 (mtan[f] @ w2T[f]) with xh+xxh epilogue ----
  {
    GemmP p{}; p.A = mtan; p.Bt = w2T; p.ldk = 64; p.kIters = 1;
    p.aStr = (size_t)BT_ * 64; p.bStr = (size_t)2048 * 64; p.oStr = (size_t)BT_ * C_;
    p.ob = xmix0; p.xh = xh; p.xxh = xxh;
    p.vArr[0] = maa_w; p.vArr[1] = maa_k; p.vArr[2] = maa_v; p.vArr[3] = maa_r; p.vArr[4] = maa_g;
    gemm_k<7><<<dim3(16, 16, 5), tb, 0, stream>>>(p);
  }

  // ---- r,k,v,g: batched-4 256^2 swizzled GEMMs ----
  {
    G256P p{}; p.Bt = WT0; p.ldk = 2048; p.nkt = 32; p.kSplit = 1;
    p.bStr = (size_t)2048 * 2048; p.oStr = (size_t)BT_ * C_; p.of = rbuf;
    p.aArr[0] = xmix0 + (size_t)3 * BT_ * C_;  // xr
    p.aArr[1] = xmix0 + (size_t)1 * BT_ * C_;  // xk
    p.aArr[2] = xmix0 + (size_t)2 * BT_ * C_;  // xv
    p.aArr[3] = xmix0 + (size_t)4 * BT_ * C_;  // xg
    gemm256<<<dim3(8, 8, 4), dim3(512), 131072, stream>>>(p);
  }

  // ---- w-path: split-K thin GEMM (xw @ td_w1), 16 chunks -> 256 blocks ----
  {
    GemmP p{}; p.A = xmix0; p.Bt = tw1T; p.ldk = 2048; p.kIters = 2; p.kChunk = 128;
    p.ldo = 128; p.pStride = (size_t)BT_ * 128; p.of = part3;
    gemm_k<5><<<dim3(1, 16, 16), tb, 0, stream>>>(p);
  }
  redk_tanh<1, 16><<<dim3(BT_ * 64 / 256), tb, 0, stream>>>(part3, (size_t)BT_ * 128, 128, 64, wtan);

  // ---- w-path: wbuf = lw = -exp(tdec + wtan @ td_w2)  (fused) ----
  {
    GemmP p{}; p.A = wtan; p.Bt = tw2T; p.ldk = 64; p.kIters = 1;
    p.of = wbuf; p.ldo = 2048; p.vArr[0] = tdec;
    gemm_k<4><<<dim3(16, 16, 1), tb, 0, stream>>>(p);
  }

  // ---- chunked WKV6 (L=32) + fused GroupNorm*silu ----
  wkv_a32<<<dim3(2048), tb, 0, stream>>>(rbuf, kbuf, vbuf, wbuf, u, rbuf, ybuf, Ubuf, Gbuf);
  wkv_b32<<<dim3(256),  tb, 0, stream>>>(Ubuf, Gbuf, Sbuf);
  wkv_c32<<<dim3(2048), tb, 0, stream>>>(rbuf, Sbuf, ybuf, gbuf, lng, lnb, ygb);

  // ---- out = yg @ Wo  (256^2 swizzled, K-split 4 -> partials -> sum) ----
  {
    G256P p{}; p.Bt = WT0 + (size_t)4 * 2048 * 2048; p.ldk = 2048;
    p.nkt = 8; p.kSplit = 4;
    p.bStr = 0; p.oStr = (size_t)2048 * 2048; p.of = partW;
    p.aArr[0] = ygb;
    gemm256<<<dim3(8, 8, 4), dim3(512), 131072, stream>>>(p);
  }
  redk_sum4<<<dim3(4096), tb, 0, stream>>>(partW, out);
}